// Round 4
// baseline (423.174 us; speedup 1.0000x reference)
//
#include <hip/hip_runtime.h>
#include <hip/hip_bf16.h>

// Problem constants (from setup_inputs)
#define N_EMB   6272
#define M_BANK  32768
#define D_DIM   128
#define KPACK   384      // hi|hi|lo vs hi|lo|hi packed K
#define BATCH   8
#define P_PATCH 784      // 6272 / 8
#define GRID_WH 28
#define OUT_WH  224
#define KNN     9
#define KSIZE   33
#define KRAD    16

typedef unsigned long long ull;
typedef short bf16x8 __attribute__((ext_vector_type(8)));
typedef float f32x4  __attribute__((ext_vector_type(4)));

// ---------------- workspace layout (bytes), ws ~256 MB ----------------
#define WS_MINPACK 0          // u64[6272]            -> 50176
#define WS_X2      50176      // f32[6272]            -> 75264
#define WS_Y2      75264      // f32[32768]           -> 206336
#define WS_PSCORE  206336     // f32[6272]            -> 231424
#define WS_BSCORE  231424     // f32[8]
#define WS_BMAXP   231456     // i32[8]
#define WS_BNN     231488     // i32[8]
#define WS_DNN     231552     // f32[8*32768]         -> 1280128
#define WS_APK     2885888    // u16[6272*384]        -> 7702784   (16B aligned)
#define WS_BPK     7702784    // u16[32768*384]       -> 32868608  (16B aligned)
#define WS_CAND    32868608   // u64[8*32*9]          -> 32887040

__device__ __forceinline__ ull umin64(ull a, ull b) { return a < b ? a : b; }
__device__ __forceinline__ ull umax64(ull a, ull b) { return a > b ? a : b; }

__device__ __forceinline__ void gload_lds16(const void* g, void* l) {
    __builtin_amdgcn_global_load_lds(
        (const __attribute__((address_space(1))) void*)g,
        (__attribute__((address_space(3))) void*)l, 16, 0, 0);
}

// ---------------------------------------------------------------------------
// Kernel 0 (prep): per-row bf16 hi/lo split-pack + sum-of-squares + minpack init.
// One wave per row. A rows: [hi|hi|lo]; B rows: [hi|lo|hi].
// ---------------------------------------------------------------------------
__global__ __launch_bounds__(256) void prep_kernel(
    const float* __restrict__ emb, const float* __restrict__ bank,
    unsigned short* __restrict__ Apk, unsigned short* __restrict__ Bpk,
    float* __restrict__ x2, float* __restrict__ y2, ull* __restrict__ minpack)
{
    const int tid = threadIdx.x;
    int gi = blockIdx.x * 256 + tid;
    if (gi < N_EMB) minpack[gi] = ~0ull;

    const int w    = blockIdx.x * 4 + (tid >> 6);
    const int lane = tid & 63;
    const float* src;
    unsigned short* dst;
    float* sq;
    int loOff, hi2Off;
    if (w < N_EMB) {
        src = emb + (size_t)w * D_DIM;
        dst = Apk + (size_t)w * KPACK;
        sq  = x2 + w;
        hi2Off = 128; loOff = 256;     // A: hi, hi, lo
    } else {
        int m = w - N_EMB;             // grid sized exactly -> m < M_BANK
        src = bank + (size_t)m * D_DIM;
        dst = Bpk + (size_t)m * KPACK;
        sq  = y2 + m;
        loOff = 128; hi2Off = 256;     // B: hi, lo, hi
    }
    float2 v = *(const float2*)&src[2 * lane];
    __hip_bfloat16 h0 = __float2bfloat16(v.x);
    __hip_bfloat16 h1 = __float2bfloat16(v.y);
    __hip_bfloat16 l0 = __float2bfloat16(v.x - __bfloat162float(h0));
    __hip_bfloat16 l1 = __float2bfloat16(v.y - __bfloat162float(h1));
    unsigned hb0 = *(unsigned short*)&h0, hb1 = *(unsigned short*)&h1;
    unsigned lb0 = *(unsigned short*)&l0, lb1 = *(unsigned short*)&l1;
    unsigned hpack = hb0 | (hb1 << 16);
    unsigned lpack = lb0 | (lb1 << 16);
    *(unsigned*)&dst[2 * lane]          = hpack;
    *(unsigned*)&dst[hi2Off + 2 * lane] = hpack;
    *(unsigned*)&dst[loOff + 2 * lane]  = lpack;

    float s = fmaf(v.x, v.x, v.y * v.y);
    #pragma unroll
    for (int off = 32; off > 0; off >>= 1) s += __shfl_down(s, off, 64);
    if (lane == 0) *sq = s;
}

// ---------------------------------------------------------------------------
// Kernel 1: MFMA distance + fused min/argmin.
// 128x128 tile, 16x16x32 bf16 MFMA, K=384 (hi/lo split), global_load_lds
// width-16 staging. XCD-aware swizzle: xcd = blk & 7 owns a band of 32
// m-tiles (B band 3 MB -> resident in that XCD's 4 MB L2); band iterated
// m-fastest so 32 consecutive blocks share one 96 KB A strip.
// ---------------------------------------------------------------------------
__global__ __launch_bounds__(256) void mfma_min_kernel(
    const unsigned short* __restrict__ Apk, const unsigned short* __restrict__ Bpk,
    const float* __restrict__ x2, const float* __restrict__ y2,
    ull* __restrict__ minpack)
{
    __shared__ __align__(16) unsigned short Asm_[128 * 32];  // 8 KB
    __shared__ __align__(16) unsigned short Bsm_[128 * 32];  // 8 KB

    const int tid  = threadIdx.x;
    const int lane = tid & 63;
    const int wave = tid >> 6;
    const int wr = wave >> 1, wc = wave & 1;

    // XCD-aware swizzle (12544 = 8 XCDs * 49 n-tiles * 32 m-tiles)
    const int blk   = blockIdx.x;
    const int xcd   = blk & 7;
    const int local = blk >> 3;        // 0..1567
    const int nidx  = local >> 5;      // 0..48   (A strip; changes every 32 blocks)
    const int mloc  = local & 31;      // 0..31   (m within the XCD's band)
    const int n0 = nidx * 128;
    const int m0 = (xcd * 32 + mloc) * 128;

    const int srow = tid >> 2;   // 0..63 staging row
    const int sseg = tid & 3;    // 16B segment within 64B row-chunk

    const int qa = lane >> 4;    // k-quad
    const int ra = lane & 15;    // row-in-frag / col-in-C

    f32x4 acc[4][4];
    #pragma unroll
    for (int i = 0; i < 4; ++i)
        #pragma unroll
        for (int j = 0; j < 4; ++j)
            acc[i][j] = (f32x4){0.f, 0.f, 0.f, 0.f};

    for (int ks = 0; ks < KPACK; ks += 32) {
        __syncthreads();
        const size_t gA = (size_t)(n0 + srow) * KPACK + ks + sseg * 8;
        const size_t gB = (size_t)(m0 + srow) * KPACK + ks + sseg * 8;
        gload_lds16(Apk + gA,              &Asm_[srow * 32 + sseg * 8]);
        gload_lds16(Apk + gA + 64 * KPACK, &Asm_[(srow + 64) * 32 + sseg * 8]);
        gload_lds16(Bpk + gB,              &Bsm_[srow * 32 + sseg * 8]);
        gload_lds16(Bpk + gB + 64 * KPACK, &Bsm_[(srow + 64) * 32 + sseg * 8]);
        __syncthreads();

        bf16x8 af[4], bfr[4];
        #pragma unroll
        for (int i = 0; i < 4; ++i)
            af[i] = *(const bf16x8*)&Asm_[(wr * 64 + i * 16 + ra) * 32 + qa * 8];
        #pragma unroll
        for (int j = 0; j < 4; ++j)
            bfr[j] = *(const bf16x8*)&Bsm_[(wc * 64 + j * 16 + ra) * 32 + qa * 8];
        #pragma unroll
        for (int i = 0; i < 4; ++i)
            #pragma unroll
            for (int j = 0; j < 4; ++j)
                acc[i][j] = __builtin_amdgcn_mfma_f32_16x16x32_bf16(af[i], bfr[j], acc[i][j], 0, 0, 0);
    }

    // ---- epilogue: d2 = x2 + y2 - 2*dot, clamp, pack, reduce ----
    float y2v[4];
    #pragma unroll
    for (int j = 0; j < 4; ++j) y2v[j] = y2[m0 + wc * 64 + j * 16 + ra];

    __syncthreads();                 // all LDS frag reads done; reuse Asm_ as red
    ull* red = (ull*)Asm_;           // [128 rows][2 col-halves]
    #pragma unroll
    for (int i = 0; i < 4; ++i) {
        #pragma unroll
        for (int r = 0; r < 4; ++r) {
            const int rowl = wr * 64 + i * 16 + qa * 4 + r;
            const float xv = x2[n0 + rowl];
            ull mn = ~0ull;
            #pragma unroll
            for (int j = 0; j < 4; ++j) {
                const int m = m0 + wc * 64 + j * 16 + ra;
                float d2 = fmaf(-2.0f, acc[i][j][r], xv + y2v[j]);
                d2 = fmaxf(d2, 0.0f);
                ull p = ((ull)__float_as_uint(d2) << 32) | (unsigned)m;
                mn = umin64(mn, p);
            }
            #pragma unroll
            for (int s = 1; s < 16; s <<= 1)
                mn = umin64(mn, (ull)__shfl_xor(mn, s, 64));
            if (ra == 0) red[rowl * 2 + wc] = mn;
        }
    }
    __syncthreads();
    if (tid < 128)
        atomicMin(&minpack[n0 + tid], umin64(red[tid * 2], red[tid * 2 + 1]));
}

// ---------------------------------------------------------------------------
// Kernel 2: per-batch argmax of patch scores (fused unpack; argmax over d2
// == argmax over sqrt(d2)); writes pscore for the blur path.
// ---------------------------------------------------------------------------
__global__ __launch_bounds__(256) void batch_argmax_kernel(
    const ull* __restrict__ minpack, float* __restrict__ pscore,
    float* __restrict__ bscore, int* __restrict__ bmaxp, int* __restrict__ bnn)
{
    __shared__ ull red[256];
    int b = blockIdx.x, tid = threadIdx.x;
    ull local = 0;
    for (int p = tid; p < P_PATCH; p += 256) {
        ull mp = minpack[b * P_PATCH + p];
        unsigned d2b = (unsigned)(mp >> 32);
        pscore[b * P_PATCH + p] = sqrtf(__uint_as_float(d2b));
        ull pk = ((ull)d2b << 32) | (unsigned)(p ^ 0xFFFFFFFFu);
        local = umax64(local, pk);
    }
    red[tid] = local;
    __syncthreads();
    for (int s = 128; s > 0; s >>= 1) {
        if (tid < s) red[tid] = umax64(red[tid], red[tid + s]);
        __syncthreads();
    }
    if (tid == 0) {
        ull r = red[0];
        int p = (int)(((unsigned)(r & 0xFFFFFFFFu)) ^ 0xFFFFFFFFu);
        bscore[b] = sqrtf(__uint_as_float((unsigned)(r >> 32)));
        bmaxp[b]  = p;
        bnn[b]    = (int)(minpack[b * P_PATCH + p] & 0xFFFFFFFFu);
    }
}

// ---------------------------------------------------------------------------
// Kernel 3: d_nn = dist(nn_sample[b], memory_bank) -> (8, M)
// ---------------------------------------------------------------------------
__global__ __launch_bounds__(256) void dnn_kernel(
    const float* __restrict__ bank, const float* __restrict__ y2,
    const int* __restrict__ bnn, float* __restrict__ dnn)
{
    __shared__ float nn[BATCH][D_DIM];
    __shared__ float nny2[BATCH];
    int tid = threadIdx.x;
    for (int i = tid; i < BATCH * D_DIM; i += 256) {
        int b = i >> 7, d = i & 127;
        nn[b][d] = bank[(size_t)bnn[b] * D_DIM + d];
    }
    if (tid < BATCH) nny2[tid] = y2[bnn[tid]];
    __syncthreads();

    int w = tid >> 6, lane = tid & 63;
    int m = blockIdx.x * 4 + w;
    float2 v = *(const float2*)&bank[(size_t)m * D_DIM + 2 * lane];
    float part[BATCH];
    #pragma unroll
    for (int b = 0; b < BATCH; ++b)
        part[b] = fmaf(v.x, nn[b][2 * lane], v.y * nn[b][2 * lane + 1]);
    #pragma unroll
    for (int b = 0; b < BATCH; ++b) {
        float s = part[b];
        #pragma unroll
        for (int off = 32; off > 0; off >>= 1) s += __shfl_down(s, off, 64);
        if (lane == 0) {
            float d2 = nny2[b] + y2[m] - 2.0f * s;
            dnn[b * M_BANK + m] = sqrtf(fmaxf(d2, 0.0f));
        }
    }
}

// ---------------------------------------------------------------------------
// Kernel 4a: per-(batch, 1024-chunk) local top-9 of d_nn.
// ---------------------------------------------------------------------------
__global__ __launch_bounds__(256) void topk_part_kernel(
    const float* __restrict__ dnn, ull* __restrict__ cand)
{
    __shared__ ull vals[1024];
    __shared__ ull red[256];
    const int tid = threadIdx.x;
    const int b = blockIdx.y, ch = blockIdx.x;
    const int base = ch * 1024;

    #pragma unroll
    for (int j = 0; j < 4; ++j) {
        int i = base + tid + j * 256;
        vals[tid + j * 256] = ((ull)__float_as_uint(dnn[b * M_BANK + i]) << 32) | (unsigned)i;
    }
    __syncthreads();

    for (int k = 0; k < KNN; ++k) {
        ull local = vals[tid];
        #pragma unroll
        for (int j = 1; j < 4; ++j) local = umin64(local, vals[tid + j * 256]);
        red[tid] = local;
        __syncthreads();
        for (int s = 128; s > 0; s >>= 1) {
            if (tid < s) red[tid] = umin64(red[tid], red[tid + s]);
            __syncthreads();
        }
        ull win = red[0];
        if (tid == 0) cand[(b * 32 + ch) * KNN + k] = win;
        #pragma unroll
        for (int j = 0; j < 4; ++j)
            if (vals[tid + j * 256] == win) vals[tid + j * 256] = ~0ull;
        __syncthreads();
    }
}

// ---------------------------------------------------------------------------
// Kernel 4b: per-batch final top-9 from 288 candidates + rescore
// ---------------------------------------------------------------------------
__global__ __launch_bounds__(256) void topk_final_kernel(
    const ull* __restrict__ cand,
    const float* __restrict__ emb, const float* __restrict__ bank,
    const float* __restrict__ x2, const float* __restrict__ y2,
    const float* __restrict__ bscore, const int* __restrict__ bmaxp,
    float* __restrict__ out)
{
    __shared__ ull vals[512];
    __shared__ ull red[256];
    __shared__ int chosen[KNN];
    __shared__ float dists[KNN];
    const int tid = threadIdx.x;
    const int b = blockIdx.x;

    vals[tid]       = (tid < 32 * KNN) ? cand[b * 32 * KNN + tid] : ~0ull;
    vals[tid + 256] = (tid + 256 < 32 * KNN) ? cand[b * 32 * KNN + tid + 256] : ~0ull;
    __syncthreads();

    for (int k = 0; k < KNN; ++k) {
        red[tid] = umin64(vals[tid], vals[tid + 256]);
        __syncthreads();
        for (int s = 128; s > 0; s >>= 1) {
            if (tid < s) red[tid] = umin64(red[tid], red[tid + s]);
            __syncthreads();
        }
        ull win = red[0];
        if (tid == 0) chosen[k] = (int)(win & 0xFFFFFFFFu);
        if (vals[tid] == win) vals[tid] = ~0ull;
        if (vals[tid + 256] == win) vals[tid + 256] = ~0ull;
        __syncthreads();
    }

    const int e = b * P_PATCH + bmaxp[b];
    if (tid < KNN) {
        const float* mf = emb + (size_t)e * D_DIM;
        const float* ms = bank + (size_t)chosen[tid] * D_DIM;
        float dot = 0.0f;
        for (int d = 0; d < D_DIM; ++d) dot = fmaf(mf[d], ms[d], dot);
        float d2 = x2[e] - 2.0f * dot + y2[chosen[tid]];
        dists[tid] = sqrtf(fmaxf(d2, 0.0f));
    }
    __syncthreads();
    if (tid == 0) {
        float mx = dists[0];
        for (int k = 1; k < KNN; ++k) mx = fmaxf(mx, dists[k]);
        float s = 0.0f;
        for (int k = 0; k < KNN; ++k) s += expf(dists[k] - mx);
        float w = 1.0f - expf(dists[0] - mx) / s;
        out[b] = w * bscore[b];
    }
}

// ---------------------------------------------------------------------------
// Kernel 5: fully-fused resize + separable Gaussian blur.
// Exact algebraic regroup of (bilinear resize -> v-blur -> h-blur):
//   A(yy,x)  = sum_gy rw(yy,gy) * q[gy][x]        (bilinear is separable)
//   q[gy][x] = x-interp of pscore row gy           (28 x 224)
//   hq[gy][x]= 33-tap reflect x-blur of q row gy   (28 x 224)
//   out(y,x) = sum_gy wrow[y][gy] * hq[gy][x],  wrow = v-taps collapsed
// Grid: (7 row-bands of 32, 8 batches). All intermediates in LDS.
// ---------------------------------------------------------------------------
__device__ __forceinline__ int refl224(int i) {
    if (i < 0) i = -i;
    if (i >= OUT_WH) i = 2 * (OUT_WH - 1) - i;
    return i;
}

__global__ __launch_bounds__(256) void blur_fused_kernel(
    const float* __restrict__ pscore, float* __restrict__ outp)
{
    __shared__ float g[KSIZE];
    __shared__ float ps[P_PATCH];
    __shared__ float q[GRID_WH * OUT_WH];
    __shared__ float hq[GRID_WH * OUT_WH];
    __shared__ float wrow[32][GRID_WH];

    const int tid = threadIdx.x;
    const int band = blockIdx.x;      // 0..6
    const int b    = blockIdx.y;      // 0..7

    // Gaussian taps
    if (tid < KSIZE) {
        float x = (tid - KRAD) * 0.25f;
        g[tid] = __expf(-0.5f * x * x);
    }
    for (int i = tid; i < P_PATCH; i += 256) ps[i] = pscore[b * P_PATCH + i];
    __syncthreads();
    if (tid == 0) {
        float s = 0.0f;
        for (int i = 0; i < KSIZE; ++i) s += g[i];
        float inv = 1.0f / s;
        for (int i = 0; i < KSIZE; ++i) g[i] *= inv;
    }
    __syncthreads();

    // q[gy][x]: x-direction bilinear interp of ps
    for (int i = tid; i < GRID_WH * OUT_WH; i += 256) {
        int gy = i / OUT_WH, x = i - gy * OUT_WH;
        float cx = (2 * x - 7) * 0.0625f;
        int ix = (int)floorf(cx); float fx = cx - ix;
        int x0 = min(max(ix, 0), GRID_WH - 1), x1 = min(max(ix + 1, 0), GRID_WH - 1);
        q[i] = ps[gy * GRID_WH + x0] * (1.0f - fx) + ps[gy * GRID_WH + x1] * fx;
    }

    // wrow[yl][gy]: vertical taps (reflect + bilinear row weights) collapsed
    if (tid < 32) {
        int y = band * 32 + tid;
        for (int gy = 0; gy < GRID_WH; ++gy) wrow[tid][gy] = 0.0f;
        for (int t = 0; t < KSIZE; ++t) {
            int yy = refl224(y - KRAD + t);
            float cy = (2 * yy - 7) * 0.0625f;
            int iy = (int)floorf(cy); float fy = cy - iy;
            int y0 = min(max(iy, 0), GRID_WH - 1), y1 = min(max(iy + 1, 0), GRID_WH - 1);
            wrow[tid][y0] += g[t] * (1.0f - fy);
            wrow[tid][y1] += g[t] * fy;
        }
    }
    __syncthreads();

    // hq[gy][x]: horizontal 33-tap reflect blur of q
    for (int i = tid; i < GRID_WH * OUT_WH; i += 256) {
        int gy = i / OUT_WH, x = i - gy * OUT_WH;
        float s = 0.0f;
        #pragma unroll
        for (int t = 0; t < KSIZE; ++t)
            s = fmaf(g[t], q[gy * OUT_WH + refl224(x - KRAD + t)], s);
        hq[i] = s;
    }
    __syncthreads();

    // out(y,x) = sum_gy wrow * hq
    const int yl = tid >> 3;                 // 0..31
    const int xbase = (tid & 7) * 28;        // 8 groups x 28 px = 224
    const int y = band * 32 + yl;
    float* orow = outp + ((size_t)b * OUT_WH + y) * OUT_WH;
    for (int i = 0; i < 28; ++i) {
        int x = xbase + i;
        float s = 0.0f;
        #pragma unroll
        for (int gy = 0; gy < GRID_WH; ++gy)
            s = fmaf(wrow[yl][gy], hq[gy * OUT_WH + x], s);
        orow[x] = s;
    }
}

// ---------------------------------------------------------------------------
extern "C" void kernel_launch(void* const* d_in, const int* in_sizes, int n_in,
                              void* d_out, int out_size, void* d_ws, size_t ws_size,
                              hipStream_t stream) {
    const float* emb  = (const float*)d_in[0];
    const float* bank = (const float*)d_in[1];
    float* out = (float*)d_out;

    char* ws = (char*)d_ws;
    ull*   minpack = (ull*)(ws + WS_MINPACK);
    float* x2      = (float*)(ws + WS_X2);
    float* y2      = (float*)(ws + WS_Y2);
    float* pscore  = (float*)(ws + WS_PSCORE);
    float* bscore  = (float*)(ws + WS_BSCORE);
    int*   bmaxp   = (int*)(ws + WS_BMAXP);
    int*   bnn     = (int*)(ws + WS_BNN);
    float* dnn     = (float*)(ws + WS_DNN);
    unsigned short* Apk = (unsigned short*)(ws + WS_APK);
    unsigned short* Bpk = (unsigned short*)(ws + WS_BPK);
    ull*   cand    = (ull*)(ws + WS_CAND);

    // 0: split-pack + sumsq + minpack init (one wave per row)
    prep_kernel<<<(N_EMB + M_BANK) / 4, 256, 0, stream>>>(emb, bank, Apk, Bpk, x2, y2, minpack);
    // 1: MFMA distance + fused min/argmin (XCD-swizzled 1-D grid)
    mfma_min_kernel<<<(M_BANK / 128) * (N_EMB / 128), 256, 0, stream>>>(Apk, Bpk, x2, y2, minpack);
    // 2: per-batch argmax (+ pscore unpack)
    batch_argmax_kernel<<<BATCH, 256, 0, stream>>>(minpack, pscore, bscore, bmaxp, bnn);
    // 3: d_nn
    dnn_kernel<<<M_BANK / 4, 256, 0, stream>>>(bank, y2, bnn, dnn);
    // 4a: per-chunk top-9 candidates
    {
        dim3 grid(32, BATCH);
        topk_part_kernel<<<grid, 256, 0, stream>>>(dnn, cand);
    }
    // 4b: final top-9 + rescore -> out[0..7]
    topk_final_kernel<<<BATCH, 256, 0, stream>>>(cand, emb, bank, x2, y2, bscore, bmaxp, out);
    // 5: fused resize + full separable blur -> out[8..]
    {
        dim3 grid(OUT_WH / 32, BATCH);
        blur_fused_kernel<<<grid, 256, 0, stream>>>(pscore, out + BATCH);
    }
}

// Round 5
// 410.232 us; speedup vs baseline: 1.0315x; 1.0315x over previous
//
#include <hip/hip_runtime.h>
#include <hip/hip_bf16.h>

// Problem constants (from setup_inputs)
#define N_EMB   6272
#define M_BANK  32768
#define D_DIM   128
#define KPACK   384      // hi|hi|lo vs hi|lo|hi packed K
#define BATCH   8
#define P_PATCH 784      // 6272 / 8
#define GRID_WH 28
#define OUT_WH  224
#define KNN     9
#define KSIZE   33
#define KRAD    16

typedef unsigned long long ull;
typedef short bf16x8 __attribute__((ext_vector_type(8)));
typedef float f32x4  __attribute__((ext_vector_type(4)));

// ---------------- workspace layout (bytes), ws ~256 MB ----------------
#define WS_MINPACK 0          // u64[6272]            -> 50176
#define WS_X2      50176      // f32[6272]            -> 75264
#define WS_Y2      75264      // f32[32768]           -> 206336
#define WS_PSCORE  206336     // f32[6272]            -> 231424
#define WS_BSCORE  231424     // f32[8]
#define WS_BMAXP   231456     // i32[8]
#define WS_BNN     231488     // i32[8]
#define WS_DNN     231552     // f32[8*32768]         -> 1280128
#define WS_APK     2885888    // u16[6272*384]        -> 7702784   (16B aligned)
#define WS_BPK     7702784    // u16[32768*384]       -> 32868608  (16B aligned)
#define WS_CAND    32868608   // u64[8*32*9]          -> 32887040

__device__ __forceinline__ ull umin64(ull a, ull b) { return a < b ? a : b; }
__device__ __forceinline__ ull umax64(ull a, ull b) { return a > b ? a : b; }

__device__ __forceinline__ void gload_lds16(const void* g, void* l) {
    __builtin_amdgcn_global_load_lds(
        (const __attribute__((address_space(1))) void*)g,
        (__attribute__((address_space(3))) void*)l, 16, 0, 0);
}

// ---------------------------------------------------------------------------
// Kernel 0 (prep): per-row bf16 hi/lo split-pack + sum-of-squares + minpack init.
// One wave per row. A rows: [hi|hi|lo]; B rows: [hi|lo|hi].
// ---------------------------------------------------------------------------
__global__ __launch_bounds__(256) void prep_kernel(
    const float* __restrict__ emb, const float* __restrict__ bank,
    unsigned short* __restrict__ Apk, unsigned short* __restrict__ Bpk,
    float* __restrict__ x2, float* __restrict__ y2, ull* __restrict__ minpack)
{
    const int tid = threadIdx.x;
    int gi = blockIdx.x * 256 + tid;
    if (gi < N_EMB) minpack[gi] = ~0ull;

    const int w    = blockIdx.x * 4 + (tid >> 6);
    const int lane = tid & 63;
    const float* src;
    unsigned short* dst;
    float* sq;
    int loOff, hi2Off;
    if (w < N_EMB) {
        src = emb + (size_t)w * D_DIM;
        dst = Apk + (size_t)w * KPACK;
        sq  = x2 + w;
        hi2Off = 128; loOff = 256;     // A: hi, hi, lo
    } else {
        int m = w - N_EMB;             // grid sized exactly -> m < M_BANK
        src = bank + (size_t)m * D_DIM;
        dst = Bpk + (size_t)m * KPACK;
        sq  = y2 + m;
        loOff = 128; hi2Off = 256;     // B: hi, lo, hi
    }
    float2 v = *(const float2*)&src[2 * lane];
    __hip_bfloat16 h0 = __float2bfloat16(v.x);
    __hip_bfloat16 h1 = __float2bfloat16(v.y);
    __hip_bfloat16 l0 = __float2bfloat16(v.x - __bfloat162float(h0));
    __hip_bfloat16 l1 = __float2bfloat16(v.y - __bfloat162float(h1));
    unsigned hb0 = *(unsigned short*)&h0, hb1 = *(unsigned short*)&h1;
    unsigned lb0 = *(unsigned short*)&l0, lb1 = *(unsigned short*)&l1;
    unsigned hpack = hb0 | (hb1 << 16);
    unsigned lpack = lb0 | (lb1 << 16);
    *(unsigned*)&dst[2 * lane]          = hpack;
    *(unsigned*)&dst[hi2Off + 2 * lane] = hpack;
    *(unsigned*)&dst[loOff + 2 * lane]  = lpack;

    float s = fmaf(v.x, v.x, v.y * v.y);
    #pragma unroll
    for (int off = 32; off > 0; off >>= 1) s += __shfl_down(s, off, 64);
    if (lane == 0) *sq = s;
}

// ---------------------------------------------------------------------------
// Kernel 1: MFMA distance + fused min/argmin.
// 128x128 tile, 16x16x32 bf16 MFMA, K=384 (hi/lo split).
// DOUBLE-BUFFERED global_load_lds pipeline with raw s_barrier + vmcnt(4):
// prefetch of chunk k+1 stays in flight across chunk k's compute (the
// __syncthreads structure would drain vmcnt(0) at every barrier).
// Race safety: barrier#1 = all waves consumed buf[nxt] (frag reads are
// consumed by MFMA in program order before it); per-wave vmcnt wait +
// barrier#2 = buf[cur] fully DMA'd in all waves.
// ---------------------------------------------------------------------------
__global__ __launch_bounds__(256) void mfma_min_kernel(
    const unsigned short* __restrict__ Apk, const unsigned short* __restrict__ Bpk,
    const float* __restrict__ x2, const float* __restrict__ y2,
    ull* __restrict__ minpack)
{
    __shared__ __align__(16) unsigned short Asm_[2][128 * 32];  // 16 KB
    __shared__ __align__(16) unsigned short Bsm_[2][128 * 32];  // 16 KB

    const int tid  = threadIdx.x;
    const int lane = tid & 63;
    const int wave = tid >> 6;
    const int wr = wave >> 1, wc = wave & 1;
    const int n0 = blockIdx.y * 128;
    const int m0 = blockIdx.x * 128;

    const int srow = tid >> 2;   // 0..63 staging row
    const int sseg = tid & 3;    // 16B segment within 64B row-chunk

    const int qa = lane >> 4;    // k-quad
    const int ra = lane & 15;    // row-in-frag / col-in-C

    f32x4 acc[4][4];
    #pragma unroll
    for (int i = 0; i < 4; ++i)
        #pragma unroll
        for (int j = 0; j < 4; ++j)
            acc[i][j] = (f32x4){0.f, 0.f, 0.f, 0.f};

    const unsigned short* gA = Apk + (size_t)(n0 + srow) * KPACK + sseg * 8;
    const unsigned short* gB = Bpk + (size_t)(m0 + srow) * KPACK + sseg * 8;
    const int lofA = srow * 32 + sseg * 8;            // lane's LDS elem offset
    const int lofB = (srow + 64) * 32 + sseg * 8;
    const int BUFE = 128 * 32;                        // elems per buffer

    // prologue: chunk 0 -> buffer 0
    gload_lds16(gA,              &Asm_[0][lofA]);
    gload_lds16(gA + 64 * KPACK, &Asm_[0][lofB]);
    gload_lds16(gB,              &Bsm_[0][lofA]);
    gload_lds16(gB + 64 * KPACK, &Bsm_[0][lofB]);

    for (int k = 0; k < 12; ++k) {
        const int cur = k & 1;
        const int nxt = cur ^ 1;
        // barrier#1: everyone is done reading buf[nxt] (cur of iter k-1)
        asm volatile("s_barrier" ::: "memory");
        if (k < 11) {
            const int ko = (k + 1) * 32;
            gload_lds16(gA + ko,              &Asm_[0][nxt * BUFE + lofA]);
            gload_lds16(gA + ko + 64 * KPACK, &Asm_[0][nxt * BUFE + lofB]);
            gload_lds16(gB + ko,              &Bsm_[0][nxt * BUFE + lofA]);
            gload_lds16(gB + ko + 64 * KPACK, &Bsm_[0][nxt * BUFE + lofB]);
            // 4 newest (prefetch) may remain in flight; cur's 4 are older
            asm volatile("s_waitcnt vmcnt(4)" ::: "memory");
        } else {
            asm volatile("s_waitcnt vmcnt(0)" ::: "memory");
        }
        // barrier#2: buf[cur] complete in every wave
        asm volatile("s_barrier" ::: "memory");

        const unsigned short* As = &Asm_[0][cur * BUFE];
        const unsigned short* Bs = &Bsm_[0][cur * BUFE];
        bf16x8 af[4], bfr[4];
        #pragma unroll
        for (int i = 0; i < 4; ++i)
            af[i] = *(const bf16x8*)&As[(wr * 64 + i * 16 + ra) * 32 + qa * 8];
        #pragma unroll
        for (int j = 0; j < 4; ++j)
            bfr[j] = *(const bf16x8*)&Bs[(wc * 64 + j * 16 + ra) * 32 + qa * 8];
        #pragma unroll
        for (int i = 0; i < 4; ++i)
            #pragma unroll
            for (int j = 0; j < 4; ++j)
                acc[i][j] = __builtin_amdgcn_mfma_f32_16x16x32_bf16(af[i], bfr[j], acc[i][j], 0, 0, 0);
    }

    // ---- epilogue: d2 = x2 + y2 - 2*dot, clamp, pack, reduce ----
    // red lives in buffer 0 of Asm_ (2 KB); last-iter frag reads were from
    // buffer 1 (cur of k=11), so no barrier needed before writing red.
    float y2v[4];
    #pragma unroll
    for (int j = 0; j < 4; ++j) y2v[j] = y2[m0 + wc * 64 + j * 16 + ra];

    ull* red = (ull*)&Asm_[0][0];    // [128 rows][2 col-halves]
    #pragma unroll
    for (int i = 0; i < 4; ++i) {
        #pragma unroll
        for (int r = 0; r < 4; ++r) {
            const int rowl = wr * 64 + i * 16 + qa * 4 + r;
            const float xv = x2[n0 + rowl];
            ull mn = ~0ull;
            #pragma unroll
            for (int j = 0; j < 4; ++j) {
                const int m = m0 + wc * 64 + j * 16 + ra;
                float d2 = fmaf(-2.0f, acc[i][j][r], xv + y2v[j]);
                d2 = fmaxf(d2, 0.0f);
                ull p = ((ull)__float_as_uint(d2) << 32) | (unsigned)m;
                mn = umin64(mn, p);
            }
            #pragma unroll
            for (int s = 1; s < 16; s <<= 1)
                mn = umin64(mn, (ull)__shfl_xor(mn, s, 64));
            if (ra == 0) red[rowl * 2 + wc] = mn;
        }
    }
    __syncthreads();
    if (tid < 128)
        atomicMin(&minpack[n0 + tid], umin64(red[tid * 2], red[tid * 2 + 1]));
}

// ---------------------------------------------------------------------------
// Kernel 2: per-batch argmax of patch scores (fused unpack; argmax over d2
// == argmax over sqrt(d2)); writes pscore for the blur path.
// ---------------------------------------------------------------------------
__global__ __launch_bounds__(256) void batch_argmax_kernel(
    const ull* __restrict__ minpack, float* __restrict__ pscore,
    float* __restrict__ bscore, int* __restrict__ bmaxp, int* __restrict__ bnn)
{
    __shared__ ull red[256];
    int b = blockIdx.x, tid = threadIdx.x;
    ull local = 0;
    for (int p = tid; p < P_PATCH; p += 256) {
        ull mp = minpack[b * P_PATCH + p];
        unsigned d2b = (unsigned)(mp >> 32);
        pscore[b * P_PATCH + p] = sqrtf(__uint_as_float(d2b));
        ull pk = ((ull)d2b << 32) | (unsigned)(p ^ 0xFFFFFFFFu);
        local = umax64(local, pk);
    }
    red[tid] = local;
    __syncthreads();
    for (int s = 128; s > 0; s >>= 1) {
        if (tid < s) red[tid] = umax64(red[tid], red[tid + s]);
        __syncthreads();
    }
    if (tid == 0) {
        ull r = red[0];
        int p = (int)(((unsigned)(r & 0xFFFFFFFFu)) ^ 0xFFFFFFFFu);
        bscore[b] = sqrtf(__uint_as_float((unsigned)(r >> 32)));
        bmaxp[b]  = p;
        bnn[b]    = (int)(minpack[b * P_PATCH + p] & 0xFFFFFFFFu);
    }
}

// ---------------------------------------------------------------------------
// Kernel 3: d_nn = dist(nn_sample[b], memory_bank) -> (8, M)
// ---------------------------------------------------------------------------
__global__ __launch_bounds__(256) void dnn_kernel(
    const float* __restrict__ bank, const float* __restrict__ y2,
    const int* __restrict__ bnn, float* __restrict__ dnn)
{
    __shared__ float nn[BATCH][D_DIM];
    __shared__ float nny2[BATCH];
    int tid = threadIdx.x;
    for (int i = tid; i < BATCH * D_DIM; i += 256) {
        int b = i >> 7, d = i & 127;
        nn[b][d] = bank[(size_t)bnn[b] * D_DIM + d];
    }
    if (tid < BATCH) nny2[tid] = y2[bnn[tid]];
    __syncthreads();

    int w = tid >> 6, lane = tid & 63;
    int m = blockIdx.x * 4 + w;
    float2 v = *(const float2*)&bank[(size_t)m * D_DIM + 2 * lane];
    float part[BATCH];
    #pragma unroll
    for (int b = 0; b < BATCH; ++b)
        part[b] = fmaf(v.x, nn[b][2 * lane], v.y * nn[b][2 * lane + 1]);
    #pragma unroll
    for (int b = 0; b < BATCH; ++b) {
        float s = part[b];
        #pragma unroll
        for (int off = 32; off > 0; off >>= 1) s += __shfl_down(s, off, 64);
        if (lane == 0) {
            float d2 = nny2[b] + y2[m] - 2.0f * s;
            dnn[b * M_BANK + m] = sqrtf(fmaxf(d2, 0.0f));
        }
    }
}

// ---------------------------------------------------------------------------
// Kernel 4a: per-(batch, 1024-chunk) local top-9 of d_nn.
// ---------------------------------------------------------------------------
__global__ __launch_bounds__(256) void topk_part_kernel(
    const float* __restrict__ dnn, ull* __restrict__ cand)
{
    __shared__ ull vals[1024];
    __shared__ ull red[256];
    const int tid = threadIdx.x;
    const int b = blockIdx.y, ch = blockIdx.x;
    const int base = ch * 1024;

    #pragma unroll
    for (int j = 0; j < 4; ++j) {
        int i = base + tid + j * 256;
        vals[tid + j * 256] = ((ull)__float_as_uint(dnn[b * M_BANK + i]) << 32) | (unsigned)i;
    }
    __syncthreads();

    for (int k = 0; k < KNN; ++k) {
        ull local = vals[tid];
        #pragma unroll
        for (int j = 1; j < 4; ++j) local = umin64(local, vals[tid + j * 256]);
        red[tid] = local;
        __syncthreads();
        for (int s = 128; s > 0; s >>= 1) {
            if (tid < s) red[tid] = umin64(red[tid], red[tid + s]);
            __syncthreads();
        }
        ull win = red[0];
        if (tid == 0) cand[(b * 32 + ch) * KNN + k] = win;
        #pragma unroll
        for (int j = 0; j < 4; ++j)
            if (vals[tid + j * 256] == win) vals[tid + j * 256] = ~0ull;
        __syncthreads();
    }
}

// ---------------------------------------------------------------------------
// Kernel 4b: per-batch final top-9 from 288 candidates + rescore
// ---------------------------------------------------------------------------
__global__ __launch_bounds__(256) void topk_final_kernel(
    const ull* __restrict__ cand,
    const float* __restrict__ emb, const float* __restrict__ bank,
    const float* __restrict__ x2, const float* __restrict__ y2,
    const float* __restrict__ bscore, const int* __restrict__ bmaxp,
    float* __restrict__ out)
{
    __shared__ ull vals[512];
    __shared__ ull red[256];
    __shared__ int chosen[KNN];
    __shared__ float dists[KNN];
    const int tid = threadIdx.x;
    const int b = blockIdx.x;

    vals[tid]       = (tid < 32 * KNN) ? cand[b * 32 * KNN + tid] : ~0ull;
    vals[tid + 256] = (tid + 256 < 32 * KNN) ? cand[b * 32 * KNN + tid + 256] : ~0ull;
    __syncthreads();

    for (int k = 0; k < KNN; ++k) {
        red[tid] = umin64(vals[tid], vals[tid + 256]);
        __syncthreads();
        for (int s = 128; s > 0; s >>= 1) {
            if (tid < s) red[tid] = umin64(red[tid], red[tid + s]);
            __syncthreads();
        }
        ull win = red[0];
        if (tid == 0) chosen[k] = (int)(win & 0xFFFFFFFFu);
        if (vals[tid] == win) vals[tid] = ~0ull;
        if (vals[tid + 256] == win) vals[tid + 256] = ~0ull;
        __syncthreads();
    }

    const int e = b * P_PATCH + bmaxp[b];
    if (tid < KNN) {
        const float* mf = emb + (size_t)e * D_DIM;
        const float* ms = bank + (size_t)chosen[tid] * D_DIM;
        float dot = 0.0f;
        for (int d = 0; d < D_DIM; ++d) dot = fmaf(mf[d], ms[d], dot);
        float d2 = x2[e] - 2.0f * dot + y2[chosen[tid]];
        dists[tid] = sqrtf(fmaxf(d2, 0.0f));
    }
    __syncthreads();
    if (tid == 0) {
        float mx = dists[0];
        for (int k = 1; k < KNN; ++k) mx = fmaxf(mx, dists[k]);
        float s = 0.0f;
        for (int k = 0; k < KNN; ++k) s += expf(dists[k] - mx);
        float w = 1.0f - expf(dists[0] - mx) / s;
        out[b] = w * bscore[b];
    }
}

// ---------------------------------------------------------------------------
// Kernel 5: fully-fused resize + separable Gaussian blur (exact regroup).
// ---------------------------------------------------------------------------
__device__ __forceinline__ int refl224(int i) {
    if (i < 0) i = -i;
    if (i >= OUT_WH) i = 2 * (OUT_WH - 1) - i;
    return i;
}

__global__ __launch_bounds__(256) void blur_fused_kernel(
    const float* __restrict__ pscore, float* __restrict__ outp)
{
    __shared__ float g[KSIZE];
    __shared__ float ps[P_PATCH];
    __shared__ float q[GRID_WH * OUT_WH];
    __shared__ float hq[GRID_WH * OUT_WH];
    __shared__ float wrow[32][GRID_WH];

    const int tid = threadIdx.x;
    const int band = blockIdx.x;      // 0..6
    const int b    = blockIdx.y;      // 0..7

    if (tid < KSIZE) {
        float x = (tid - KRAD) * 0.25f;
        g[tid] = __expf(-0.5f * x * x);
    }
    for (int i = tid; i < P_PATCH; i += 256) ps[i] = pscore[b * P_PATCH + i];
    __syncthreads();
    if (tid == 0) {
        float s = 0.0f;
        for (int i = 0; i < KSIZE; ++i) s += g[i];
        float inv = 1.0f / s;
        for (int i = 0; i < KSIZE; ++i) g[i] *= inv;
    }
    __syncthreads();

    for (int i = tid; i < GRID_WH * OUT_WH; i += 256) {
        int gy = i / OUT_WH, x = i - gy * OUT_WH;
        float cx = (2 * x - 7) * 0.0625f;
        int ix = (int)floorf(cx); float fx = cx - ix;
        int x0 = min(max(ix, 0), GRID_WH - 1), x1 = min(max(ix + 1, 0), GRID_WH - 1);
        q[i] = ps[gy * GRID_WH + x0] * (1.0f - fx) + ps[gy * GRID_WH + x1] * fx;
    }

    if (tid < 32) {
        int y = band * 32 + tid;
        for (int gy = 0; gy < GRID_WH; ++gy) wrow[tid][gy] = 0.0f;
        for (int t = 0; t < KSIZE; ++t) {
            int yy = refl224(y - KRAD + t);
            float cy = (2 * yy - 7) * 0.0625f;
            int iy = (int)floorf(cy); float fy = cy - iy;
            int y0 = min(max(iy, 0), GRID_WH - 1), y1 = min(max(iy + 1, 0), GRID_WH - 1);
            wrow[tid][y0] += g[t] * (1.0f - fy);
            wrow[tid][y1] += g[t] * fy;
        }
    }
    __syncthreads();

    for (int i = tid; i < GRID_WH * OUT_WH; i += 256) {
        int gy = i / OUT_WH, x = i - gy * OUT_WH;
        float s = 0.0f;
        #pragma unroll
        for (int t = 0; t < KSIZE; ++t)
            s = fmaf(g[t], q[gy * OUT_WH + refl224(x - KRAD + t)], s);
        hq[i] = s;
    }
    __syncthreads();

    const int yl = tid >> 3;                 // 0..31
    const int xbase = (tid & 7) * 28;        // 8 groups x 28 px = 224
    const int y = band * 32 + yl;
    float* orow = outp + ((size_t)b * OUT_WH + y) * OUT_WH;
    for (int i = 0; i < 28; ++i) {
        int x = xbase + i;
        float s = 0.0f;
        #pragma unroll
        for (int gy = 0; gy < GRID_WH; ++gy)
            s = fmaf(wrow[yl][gy], hq[gy * OUT_WH + x], s);
        orow[x] = s;
    }
}

// ---------------------------------------------------------------------------
extern "C" void kernel_launch(void* const* d_in, const int* in_sizes, int n_in,
                              void* d_out, int out_size, void* d_ws, size_t ws_size,
                              hipStream_t stream) {
    const float* emb  = (const float*)d_in[0];
    const float* bank = (const float*)d_in[1];
    float* out = (float*)d_out;

    char* ws = (char*)d_ws;
    ull*   minpack = (ull*)(ws + WS_MINPACK);
    float* x2      = (float*)(ws + WS_X2);
    float* y2      = (float*)(ws + WS_Y2);
    float* pscore  = (float*)(ws + WS_PSCORE);
    float* bscore  = (float*)(ws + WS_BSCORE);
    int*   bmaxp   = (int*)(ws + WS_BMAXP);
    int*   bnn     = (int*)(ws + WS_BNN);
    float* dnn     = (float*)(ws + WS_DNN);
    unsigned short* Apk = (unsigned short*)(ws + WS_APK);
    unsigned short* Bpk = (unsigned short*)(ws + WS_BPK);
    ull*   cand    = (ull*)(ws + WS_CAND);

    // 0: split-pack + sumsq + minpack init (one wave per row)
    prep_kernel<<<(N_EMB + M_BANK) / 4, 256, 0, stream>>>(emb, bank, Apk, Bpk, x2, y2, minpack);
    // 1: MFMA distance + fused min/argmin (2-D grid; swizzle reverted)
    {
        dim3 grid(M_BANK / 128, N_EMB / 128);   // 256 x 49
        mfma_min_kernel<<<grid, 256, 0, stream>>>(Apk, Bpk, x2, y2, minpack);
    }
    // 2: per-batch argmax (+ pscore unpack)
    batch_argmax_kernel<<<BATCH, 256, 0, stream>>>(minpack, pscore, bscore, bmaxp, bnn);
    // 3: d_nn
    dnn_kernel<<<M_BANK / 4, 256, 0, stream>>>(bank, y2, bnn, dnn);
    // 4a: per-chunk top-9 candidates
    {
        dim3 grid(32, BATCH);
        topk_part_kernel<<<grid, 256, 0, stream>>>(dnn, cand);
    }
    // 4b: final top-9 + rescore -> out[0..7]
    topk_final_kernel<<<BATCH, 256, 0, stream>>>(cand, emb, bank, x2, y2, bscore, bmaxp, out);
    // 5: fused resize + full separable blur -> out[8..]
    {
        dim3 grid(OUT_WH / 32, BATCH);
        blur_fused_kernel<<<grid, 256, 0, stream>>>(pscore, out + BATCH);
    }
}